// Round 11
// baseline (322.467 us; speedup 1.0000x reference)
//
#include <hip/hip_runtime.h>
#include <hip/hip_bf16.h>
#include <cstdint>

// LSTM cell: g[g,b,n] = sum_k A[b,k] * Wcat[g,k,n],  A = [x | h]  (K = 2048)
// i,f,o = sigmoid(g0,1,2), u = tanh(g3), c_t = i*u + f*c, h_t = o*tanh(c_t)
// Round 11: r9 GEMM (best, 154us) + pack_a ELIMINATED: A is reg-staged inside
// the GEMM (coalesced fp32 loads of x/h issued early -> MFMA hides latency ->
// RTN-even cvt -> ds_write_b128 into the same linear LDS slots). k-chunked
// layout => t<16 reads only x, t>=16 only h (uniform select). A-loads are
// younger than the B gloads needing drain, so compiler cvt-waits subsume the
// publish condition; VMW(8) is no-op insurance (tail 2/0).

#define LDS_TOTAL 131072    // 2 buf x (A 32KB + B 32KB)

typedef __attribute__((ext_vector_type(8))) short bf16x8;    // 8 bf16 = 4 VGPR
typedef __attribute__((ext_vector_type(16))) float f32x16;   // 32x32 acc
typedef __attribute__((ext_vector_type(4))) unsigned int u32x4;

static __device__ __forceinline__ unsigned short f2bf(float f) {
  union { float f; unsigned int u; } v; v.f = f;
  unsigned int u = v.u;
  unsigned int r = (u + 0x7FFFu + ((u >> 16) & 1u)) >> 16;  // RTN-even
  return (unsigned short)r;
}

static __device__ __forceinline__ void load16(const void* gp, void* lp) {
  __builtin_amdgcn_global_load_lds(
      (const __attribute__((address_space(1))) void*)gp,
      (__attribute__((address_space(3))) void*)lp, 16, 0, 0);
}

static __device__ __forceinline__ float sigmoid_f(float x) {
  return 1.0f / (1.0f + __expf(-x));
}
static __device__ __forceinline__ float tanh_f(float x) {
  float e = __expf(-2.0f * fabsf(x));
  float r = (1.0f - e) / (1.0f + e);
  return copysignf(r, x);
}

// ---- prep: W -> k-chunked bf16: Wt2[kblk 256][g 4][n 1024][8 elems] ----
__global__ __launch_bounds__(256) void prep_w_kernel(
    const float* __restrict__ Wx, const float* __restrict__ Wh,
    unsigned short* __restrict__ Wt2) {
  __shared__ float tile[64][65];
  const int g = blockIdx.x >> 9;
  const int kt = (blockIdx.x >> 4) & 31;
  const int nt = blockIdx.x & 15;
  const int k0 = kt << 6, n0 = nt << 6;
  const float* W; int ks;
  if (k0 < 1024) { W = Wx + (size_t)g * 1048576; ks = k0; }
  else           { W = Wh + (size_t)g * 1048576; ks = k0 - 1024; }
  const int r = threadIdx.x >> 4;
  const int c4 = (threadIdx.x & 15) << 2;
  #pragma unroll
  for (int s = 0; s < 4; ++s) {
    float4 v = *(const float4*)(W + (size_t)(ks + s * 16 + r) * 1024 + n0 + c4);
    tile[s * 16 + r][c4 + 0] = v.x; tile[s * 16 + r][c4 + 1] = v.y;
    tile[s * 16 + r][c4 + 2] = v.z; tile[s * 16 + r][c4 + 3] = v.w;
  }
  __syncthreads();
  #pragma unroll
  for (int i = 0; i < 2; ++i) {
    int cc = i * 256 + threadIdx.x;
    int kb = cc >> 6, nn = cc & 63;
    union { unsigned short s[8]; u32x4 v; } o;
    #pragma unroll
    for (int e = 0; e < 8; ++e) o.s[e] = f2bf(tile[kb * 8 + e][nn]);
    *(u32x4*)(Wt2 + ((size_t)((k0 >> 3) + kb) * 4096 + g * 1024 + n0 + nn) * 8) = o.v;
  }
}

#define VMW(n) asm volatile("s_waitcnt vmcnt(" #n ")" ::: "memory")
#define LGKM0() asm volatile("s_waitcnt lgkmcnt(0)" ::: "memory")
#define BAR() __builtin_amdgcn_s_barrier()

// ---- main: fused 4-gate GEMM (32x32x16) + in-kernel A pack + epilogue ----
// 512 thr = 8 waves: wr = w>>1 (rows wr*64..+64), wc = w&1 (n wc*32..+32/gate).
// LDS buf 64KB: A[4 rgn][2 khalf][256 row][16B] @0; B[4 rgn][4 g][2 kh][64 n]
// [16B] @32768 (region = 2 kblk = K16). Phase = K32 {12 ds_read + A-fp32-load
// (4 dwordx4, early) + B-stage (2 gload_lds) + VMW(8) + BAR + LGKM0 +
// 16 MFMA + cvt/ds_write A + BAR}. Stage plan (r9-verified): P0(t)->rgns{2,3}
// of t+1 (bufn); P1(t)->rgns{0,1} of t+2 (bufc).
__global__ __launch_bounds__(512, 2) void lstm_gemm_kernel(
    const float* __restrict__ x,               // [8192][1024] fp32
    const float* __restrict__ hin,             // [8192][1024] fp32
    const unsigned short* __restrict__ Wt2,    // [256 kblk][4 g][1024 n][8]
    const float* __restrict__ cprev,
    float* __restrict__ out) {
  extern __shared__ char lds[];
  const int tid = threadIdx.x;
  const int l = tid & 63;
  const int w = tid >> 6;
  const int wr = w >> 1;               // 0..3
  const int wc = w & 1;                // 0..1
  const int bid = blockIdx.x;          // 512 blocks
  const int xcd = bid & 7;             // nt-slab per XCD (W-slab L2-resident)
  const int cc = bid >> 3;
  const int nt = xcd * 2 + (cc >> 5);  // 16 n-tiles
  const int mt = cc & 31;              // 32 m-tiles
  const int m0 = mt << 8;              // BM = 256
  const int n0 = nt << 6;

  char* const buf0 = lds;
  char* const buf1 = lds + 65536;

  f32x16 acc[2][4];                    // [m-frag 32rows][gate]
  #pragma unroll
  for (int mf = 0; mf < 2; ++mf)
    #pragma unroll
    for (int g = 0; g < 4; ++g) acc[mf][g] = (f32x16)0.0f;

  const int ln = l & 31;
  const int hl = l >> 5;

  const int aBase = hl * 4096 + (wr * 64 + ln) * 16;           // +region*8192
  const int bBase = 32768 + hl * 1024 + (wc * 32 + ln) * 16;   // +region*8192

  // B staging (r9-verified): g=tid>>7, khalf=(tid>>6)&1, n=tid&63.
  const unsigned short* const gB =
      Wt2 + (size_t)((tid >> 6) & 1) * 32768 +
      (size_t)((tid >> 7) * 1024 + n0 + (tid & 63)) * 8;
  const int dB = 32768 + ((tid & ~63) << 4);
  auto stB = [&](char* buf, int j, int t) {
    load16(gB + (size_t)(t * 8 + j * 2) * 32768, buf + j * 8192 + dB);
  };

  // A reg-staging: thread covers khalf=tid>>8, row=tid&255; kblk=t*8+j*2+khalf
  // -> k = kblk*8. t<16 => x only, t>=16 => h only (clean split at kblk 128).
  const int khalf = tid >> 8;
  const float* const xrow = x   + (size_t)(m0 + (tid & 255)) * 1024;
  const float* const hrow = hin + (size_t)(m0 + (tid & 255)) * 1024;
  auto ldA = [&](int j, int t, float4& v0, float4& v1) {
    const int kk = ((t * 8 + j * 2 + khalf) * 8) & 1023;
    const float* p = ((t < 16) ? xrow : hrow) + kk;
    v0 = ((const float4*)p)[0];
    v1 = ((const float4*)p)[1];
  };
  auto wrA = [&](char* buf, int j, const float4& v0, const float4& v1) {
    union { unsigned short s[8]; u32x4 u; } o;
    o.s[0] = f2bf(v0.x); o.s[1] = f2bf(v0.y); o.s[2] = f2bf(v0.z); o.s[3] = f2bf(v0.w);
    o.s[4] = f2bf(v1.x); o.s[5] = f2bf(v1.y); o.s[6] = f2bf(v1.z); o.s[7] = f2bf(v1.w);
    *(u32x4*)(buf + j * 8192 + (tid << 4)) = o.u;
  };

  bf16x8 a_[2][2], b_[2][4];
  auto rd2 = [&](const char* bufc, int h) {     // 12 ds_read_b128, conflict-free
    #pragma unroll
    for (int r = 0; r < 2; ++r) {
      const char* pb = bufc + (2 * h + r) * 8192;
      a_[r][0] = *(const bf16x8*)(pb + aBase);
      a_[r][1] = *(const bf16x8*)(pb + aBase + 512);     // +32 rows
      b_[r][0] = *(const bf16x8*)(pb + bBase);
      b_[r][1] = *(const bf16x8*)(pb + bBase + 2048);    // +1 gate
      b_[r][2] = *(const bf16x8*)(pb + bBase + 4096);
      b_[r][3] = *(const bf16x8*)(pb + bBase + 6144);
    }
  };
  auto mfma2 = [&]() {                          // 16 MFMA
    __builtin_amdgcn_s_setprio(1);
    #pragma unroll
    for (int r = 0; r < 2; ++r)
      #pragma unroll
      for (int mf = 0; mf < 2; ++mf)
        #pragma unroll
        for (int g = 0; g < 4; ++g)
          acc[mf][g] = __builtin_amdgcn_mfma_f32_32x32x16_bf16(
              a_[r][mf], b_[r][g], acc[mf][g], 0, 0, 0);
    __builtin_amdgcn_s_setprio(0);
  };

  // Prologue: B t=0 (4) + t=1 rgns{0,1} (2); A same regions, cvt'd+written
  // (cvt waits drain everything incl. the B6 -> VMW(2) is a no-op check).
  #pragma unroll
  for (int j = 0; j < 4; ++j) stB(buf0, j, 0);
  stB(buf1, 0, 1); stB(buf1, 1, 1);
  {
    float4 u0, u1;
    #pragma unroll
    for (int j = 0; j < 4; ++j) { ldA(j, 0, u0, u1); wrA(buf0, j, u0, u1); }
    ldA(0, 1, u0, u1); wrA(buf1, 0, u0, u1);
    ldA(1, 1, u0, u1); wrA(buf1, 1, u0, u1);
  }
  LGKM0();                             // my ds_writes visible before barrier
  VMW(2);
  BAR();

  #pragma unroll 1
  for (int t = 0; t < 30; ++t) {
    char* bufc = lds + ((t & 1) << 16);
    char* bufn = lds + (((t + 1) & 1) << 16);
    float4 p0a, p0b, p1a, p1b;
    // P0: regions {0,1}; A+B for t+1 regions {2,3} -> bufn (freed @P1(t-1))
    ldA(2, t + 1, p0a, p0b); ldA(3, t + 1, p1a, p1b);   // issue early
    rd2(bufc, 0);
    stB(bufn, 2, t + 1); stB(bufn, 3, t + 1);
    VMW(8); BAR(); LGKM0();
    mfma2();
    __builtin_amdgcn_sched_barrier(0);           // keep cvt/write after MFMA
    wrA(bufn, 2, p0a, p0b); wrA(bufn, 3, p1a, p1b);
    BAR();
    // P1: regions {2,3}; A+B for t+2 regions {0,1} -> bufc (freed @P0(t))
    ldA(0, t + 2, p0a, p0b); ldA(1, t + 2, p1a, p1b);
    rd2(bufc, 1);
    stB(bufc, 0, t + 2); stB(bufc, 1, t + 2);
    VMW(8); BAR(); LGKM0();
    mfma2();
    __builtin_amdgcn_sched_barrier(0);
    wrA(bufc, 0, p0a, p0b); wrA(bufc, 1, p1a, p1b);
    BAR();
  }
  // t = 30 (bufc = buf0): P1's t+2 = 32 stages skipped -> counted tail.
  {
    float4 p0a, p0b, p1a, p1b;
    ldA(2, 31, p0a, p0b); ldA(3, 31, p1a, p1b);
    rd2(buf0, 0);
    stB(buf1, 2, 31); stB(buf1, 3, 31);
    VMW(8); BAR(); LGKM0();
    mfma2();
    __builtin_amdgcn_sched_barrier(0);
    wrA(buf1, 2, p0a, p0b); wrA(buf1, 3, p1a, p1b);
    BAR();
  }
  rd2(buf0, 1);
  VMW(2); BAR(); LGKM0(); mfma2(); BAR();
  // t = 31 (bufc = buf1)
  rd2(buf1, 0);
  VMW(0); BAR(); LGKM0(); mfma2(); BAR();
  rd2(buf1, 1);
  LGKM0(); mfma2();

  // Epilogue: 32x32 C/D layout col = lane&31, row = (r&3)+8*(r>>2)+4*(l>>5)
  // [m74/m101 verified]
  const int colB = n0 + wc * 32 + ln;
  #pragma unroll
  for (int mf = 0; mf < 2; ++mf) {
    #pragma unroll
    for (int r = 0; r < 16; ++r) {
      int row = m0 + wr * 64 + mf * 32 + (r & 3) + ((r >> 2) << 3) + (hl << 2);
      float gi = acc[mf][0][r];
      float gf = acc[mf][1][r];
      float go = acc[mf][2][r];
      float gu = acc[mf][3][r];
      float i_ = sigmoid_f(gi);
      float f_ = sigmoid_f(gf);
      float o_ = sigmoid_f(go);
      float u_ = tanh_f(gu);
      size_t idx = (size_t)row * 1024 + colB;
      float ct = i_ * u_ + f_ * cprev[idx];
      float ht = o_ * tanh_f(ct);
      out[idx] = ht;                   // h_t
      out[8388608 + idx] = ct;         // c_t
    }
  }
}

extern "C" void kernel_launch(void* const* d_in, const int* in_sizes, int n_in,
                              void* d_out, int out_size, void* d_ws, size_t ws_size,
                              hipStream_t stream) {
  const float* x  = (const float*)d_in[0];
  const float* h  = (const float*)d_in[1];
  const float* c  = (const float*)d_in[2];
  const float* Wx = (const float*)d_in[3];
  const float* Wh = (const float*)d_in[4];
  float* out = (float*)d_out;

  unsigned short* Wt2 = (unsigned short*)d_ws;   // 16,777,216 B

  hipFuncSetAttribute((const void*)lstm_gemm_kernel,
                      hipFuncAttributeMaxDynamicSharedMemorySize, LDS_TOTAL);

  prep_w_kernel<<<2048, 256, 0, stream>>>(Wx, Wh, Wt2);
  lstm_gemm_kernel<<<dim3(512), dim3(512), LDS_TOTAL, stream>>>(x, h, Wt2, c, out);
}

// Round 12
// 166.954 us; speedup vs baseline: 1.9315x; 1.9315x over previous
//
#include <hip/hip_runtime.h>
#include <hip/hip_bf16.h>
#include <cstdint>

// LSTM cell: g[g,b,n] = sum_k A[b,k] * Wcat[g,k,n],  A = [x | h]  (K = 2048)
// i,f,o = sigmoid(g0,1,2), u = tanh(g3), c_t = i*u + f*c, h_t = o*tanh(c_t)
// Round 12: r9 GEMM verbatim (best measured: ~154us, MfmaUtil 40%, 0 bank
// conflicts) + the two prep passes FUSED into one dispatch (saves a launch
// gap + packs the prep tail). r11's in-kernel A-pack reverted (row-strided
// fp32 loads doubled FETCH and broke the vmcnt ledger: 350us).

#define LDS_TOTAL 131072    // 2 buf x (A 32KB + B 32KB)

typedef __attribute__((ext_vector_type(8))) short bf16x8;    // 8 bf16 = 4 VGPR
typedef __attribute__((ext_vector_type(16))) float f32x16;   // 32x32 acc
typedef __attribute__((ext_vector_type(4))) unsigned int u32x4;

static __device__ __forceinline__ unsigned short f2bf(float f) {
  union { float f; unsigned int u; } v; v.f = f;
  unsigned int u = v.u;
  unsigned int r = (u + 0x7FFFu + ((u >> 16) & 1u)) >> 16;  // RTN-even
  return (unsigned short)r;
}

static __device__ __forceinline__ void load16(const void* gp, void* lp) {
  __builtin_amdgcn_global_load_lds(
      (const __attribute__((address_space(1))) void*)gp,
      (__attribute__((address_space(3))) void*)lp, 16, 0, 0);
}

static __device__ __forceinline__ float sigmoid_f(float x) {
  return 1.0f / (1.0f + __expf(-x));
}
static __device__ __forceinline__ float tanh_f(float x) {
  float e = __expf(-2.0f * fabsf(x));
  float r = (1.0f - e) / (1.0f + e);
  return copysignf(r, x);
}

// ---- fused prep: blocks 0..4095 pack A; blocks 4096..6143 transpose W ----
// pack A:  Ap[kblk 256][b 8192][8]  (k-chunked bf16, 64x64 LDS transpose)
// prep W:  Wt2[kblk 256][g 4][n 1024][8]
__global__ __launch_bounds__(256) void prep_fused_kernel(
    const float* __restrict__ x, const float* __restrict__ h,
    const float* __restrict__ Wx, const float* __restrict__ Wh,
    unsigned short* __restrict__ Ap, unsigned short* __restrict__ Wt2) {
  __shared__ float tile[64][65];               // pad -> no bank conflicts
  const int r = threadIdx.x >> 4;
  const int c4 = (threadIdx.x & 15) << 2;
  if (blockIdx.x < 4096) {                     // ---- pack A ----
    const int b0 = (blockIdx.x >> 5) << 6;     // 128 b-tiles
    const int k0 = (blockIdx.x & 31) << 6;     // 32 k-tiles
    const float* src; int ks;
    if (k0 < 1024) { src = x; ks = k0; } else { src = h; ks = k0 - 1024; }
    #pragma unroll
    for (int s = 0; s < 4; ++s) {
      float4 v = *(const float4*)(src + (size_t)(b0 + s * 16 + r) * 1024 + ks + c4);
      tile[s * 16 + r][c4 + 0] = v.x; tile[s * 16 + r][c4 + 1] = v.y;
      tile[s * 16 + r][c4 + 2] = v.z; tile[s * 16 + r][c4 + 3] = v.w;
    }
    __syncthreads();
    #pragma unroll
    for (int i = 0; i < 2; ++i) {
      int cc = i * 256 + threadIdx.x;
      int kb = cc >> 6, bb = cc & 63;
      union { unsigned short s[8]; u32x4 v; } o;
      #pragma unroll
      for (int e = 0; e < 8; ++e) o.s[e] = f2bf(tile[bb][kb * 8 + e]);
      *(u32x4*)(Ap + ((size_t)((k0 >> 3) + kb) * 8192 + b0 + bb) * 8) = o.v;
    }
  } else {                                     // ---- prep W ----
    const int bid = blockIdx.x - 4096;         // 2048 blocks
    const int g = bid >> 9;                    // 4 gates
    const int kt = (bid >> 4) & 31;            // 32 k-tiles
    const int nt = bid & 15;                   // 16 n-tiles
    const int k0 = kt << 6, n0 = nt << 6;
    const float* W; int ks;
    if (k0 < 1024) { W = Wx + (size_t)g * 1048576; ks = k0; }
    else           { W = Wh + (size_t)g * 1048576; ks = k0 - 1024; }
    #pragma unroll
    for (int s = 0; s < 4; ++s) {
      float4 v = *(const float4*)(W + (size_t)(ks + s * 16 + r) * 1024 + n0 + c4);
      tile[s * 16 + r][c4 + 0] = v.x; tile[s * 16 + r][c4 + 1] = v.y;
      tile[s * 16 + r][c4 + 2] = v.z; tile[s * 16 + r][c4 + 3] = v.w;
    }
    __syncthreads();
    #pragma unroll
    for (int i = 0; i < 2; ++i) {
      int cc = i * 256 + threadIdx.x;
      int kb = cc >> 6, nn = cc & 63;
      union { unsigned short s[8]; u32x4 v; } o;
      #pragma unroll
      for (int e = 0; e < 8; ++e) o.s[e] = f2bf(tile[kb * 8 + e][nn]);
      *(u32x4*)(Wt2 + ((size_t)((k0 >> 3) + kb) * 4096 + g * 1024 + n0 + nn) * 8) = o.v;
    }
  }
}

#define VMW(n) asm volatile("s_waitcnt vmcnt(" #n ")" ::: "memory")
#define LGKM0() asm volatile("s_waitcnt lgkmcnt(0)" ::: "memory")
#define BAR() __builtin_amdgcn_s_barrier()

// ---- main: fused 4-gate GEMM (32x32x16 MFMA) + LSTM epilogue (r9 exact) ----
// 512 thr = 8 waves: wr = w>>1 (rows wr*64..+64), wc = w&1 (n wc*32..+32/gate).
// LDS buf 64KB: A[4 ksub][2 half][256 row][16B] @0; B[4 ksub][4 g][2 half]
// [64 n][16B] @32768. Phase h covers regions {2h,2h+1} (K=32): 12 ds_read +
// 4 gload_lds + vmcnt(8) + bar + lgkm0 + 16 MFMA + bar. Stage plan:
// P0(t) -> regions{2,3} of t+1 (bufn, freed @P1(t-1)); P1(t) -> regions{0,1}
// of t+2 (bufc, freed @P0(t)). Uniform vmcnt(8), tail 8/4/0.
__global__ __launch_bounds__(512, 2) void lstm_gemm_kernel(
    const unsigned short* __restrict__ Ap,     // [256 kblk][8192 b][8]
    const unsigned short* __restrict__ Wt2,    // [256 kblk][4 g][1024 n][8]
    const float* __restrict__ cprev,
    float* __restrict__ out) {
  extern __shared__ char lds[];
  const int tid = threadIdx.x;
  const int l = tid & 63;
  const int w = tid >> 6;
  const int wr = w >> 1;               // 0..3
  const int wc = w & 1;                // 0..1
  const int bid = blockIdx.x;          // 512 blocks
  const int xcd = bid & 7;             // nt-slab per XCD
  const int cc = bid >> 3;
  const int nt = xcd * 2 + (cc >> 5);  // 16 n-tiles
  const int mt = cc & 31;              // 32 m-tiles
  const int m0 = mt << 8;
  const int n0 = nt << 6;

  char* const buf0 = lds;
  char* const buf1 = lds + 65536;

  f32x16 acc[2][4];                    // [m-frag 32rows][gate]
  #pragma unroll
  for (int mf = 0; mf < 2; ++mf)
    #pragma unroll
    for (int g = 0; g < 4; ++g) acc[mf][g] = (f32x16)0.0f;

  const int ln = l & 31;
  const int hl = l >> 5;               // k-group: k = hl*8 + e

  const int aBase = hl * 4096 + (wr * 64 + ln) * 16;           // +region*8192
  const int bBase = 32768 + hl * 1024 + (wc * 32 + ln) * 16;   // +region*8192

  const unsigned short* const gA =
      Ap + (size_t)(tid >> 8) * 65536 + (size_t)(m0 + (tid & 255)) * 8;
  const unsigned short* const gB =
      Wt2 + (size_t)((tid >> 6) & 1) * 32768 +
      (size_t)((tid >> 7) * 1024 + n0 + (tid & 63)) * 8;
  const int dA = (tid & ~63) << 4;
  const int dB = 32768 + ((tid & ~63) << 4);

  auto stPair = [&](char* buf, int j, int t) {  // region j of tile t (A+B)
    load16(gA + (size_t)(t * 8 + j * 2) * 65536, buf + j * 8192 + dA);
    load16(gB + (size_t)(t * 8 + j * 2) * 32768, buf + j * 8192 + dB);
  };

  bf16x8 a_[2][2], b_[2][4];
  auto rd2 = [&](const char* bufc, int h) {     // 12 ds_read_b128, conflict-free
    #pragma unroll
    for (int r = 0; r < 2; ++r) {
      const char* pb = bufc + (2 * h + r) * 8192;
      a_[r][0] = *(const bf16x8*)(pb + aBase);
      a_[r][1] = *(const bf16x8*)(pb + aBase + 512);
      b_[r][0] = *(const bf16x8*)(pb + bBase);
      b_[r][1] = *(const bf16x8*)(pb + bBase + 2048);
      b_[r][2] = *(const bf16x8*)(pb + bBase + 4096);
      b_[r][3] = *(const bf16x8*)(pb + bBase + 6144);
    }
  };
  auto mfma2 = [&]() {                          // 16 MFMA
    __builtin_amdgcn_s_setprio(1);
    #pragma unroll
    for (int r = 0; r < 2; ++r)
      #pragma unroll
      for (int mf = 0; mf < 2; ++mf)
        #pragma unroll
        for (int g = 0; g < 4; ++g)
          acc[mf][g] = __builtin_amdgcn_mfma_f32_32x32x16_bf16(
              a_[r][mf], b_[r][g], acc[mf][g], 0, 0, 0);
    __builtin_amdgcn_s_setprio(0);
  };

  // Prologue: t=0 all 4 regions -> buf0 (8 loads); t=1 regions{0,1} -> buf1.
  #pragma unroll
  for (int j = 0; j < 4; ++j) stPair(buf0, j, 0);
  stPair(buf1, 0, 1); stPair(buf1, 1, 1);
  VMW(4);
  BAR();

  #pragma unroll 1
  for (int t = 0; t < 30; ++t) {
    char* bufc = lds + ((t & 1) << 16);
    char* bufn = lds + (((t + 1) & 1) << 16);
    // P0: regions {0,1}; stage t+1 regions {2,3} (bufn, freed @P1(t-1))
    rd2(bufc, 0);
    stPair(bufn, 2, t + 1); stPair(bufn, 3, t + 1);
    VMW(8); BAR(); LGKM0();
    mfma2();
    BAR();
    // P1: regions {2,3}; stage t+2 regions {0,1} (bufc, freed @P0(t))
    rd2(bufc, 1);
    stPair(bufc, 0, t + 2); stPair(bufc, 1, t + 2);
    VMW(8); BAR(); LGKM0();
    mfma2();
    BAR();
  }
  // t=30 (bufc=buf0, bufn=buf1): P1 stage (t+2=32) skipped -> tail counts.
  rd2(buf0, 0); stPair(buf1, 2, 31); stPair(buf1, 3, 31);
  VMW(8); BAR(); LGKM0(); mfma2(); BAR();
  rd2(buf0, 1);
  VMW(4); BAR(); LGKM0(); mfma2(); BAR();
  // t=31 (bufc=buf1): no stages.
  rd2(buf1, 0);
  VMW(0); BAR(); LGKM0(); mfma2(); BAR();
  rd2(buf1, 1);
  LGKM0(); mfma2();

  // Epilogue: 32x32 C/D layout col = lane&31, row = (r&3)+8*(r>>2)+4*(l>>5)
  const int colB = n0 + wc * 32 + ln;
  #pragma unroll
  for (int mf = 0; mf < 2; ++mf) {
    #pragma unroll
    for (int r = 0; r < 16; ++r) {
      int row = m0 + wr * 64 + mf * 32 + (r & 3) + ((r >> 2) << 3) + (hl << 2);
      float gi = acc[mf][0][r];
      float gf = acc[mf][1][r];
      float go = acc[mf][2][r];
      float gu = acc[mf][3][r];
      float i_ = sigmoid_f(gi);
      float f_ = sigmoid_f(gf);
      float o_ = sigmoid_f(go);
      float u_ = tanh_f(gu);
      size_t idx = (size_t)row * 1024 + colB;
      float ct = i_ * u_ + f_ * cprev[idx];
      float ht = o_ * tanh_f(ct);
      out[idx] = ht;                   // h_t
      out[8388608 + idx] = ct;         // c_t
    }
  }
}

extern "C" void kernel_launch(void* const* d_in, const int* in_sizes, int n_in,
                              void* d_out, int out_size, void* d_ws, size_t ws_size,
                              hipStream_t stream) {
  const float* x  = (const float*)d_in[0];
  const float* h  = (const float*)d_in[1];
  const float* c  = (const float*)d_in[2];
  const float* Wx = (const float*)d_in[3];
  const float* Wh = (const float*)d_in[4];
  float* out = (float*)d_out;

  unsigned short* Ap  = (unsigned short*)d_ws;                   // 33,554,432 B
  unsigned short* Wt2 = (unsigned short*)((char*)d_ws + 33554432); // 16,777,216 B

  hipFuncSetAttribute((const void*)lstm_gemm_kernel,
                      hipFuncAttributeMaxDynamicSharedMemorySize, LDS_TOTAL);

  prep_fused_kernel<<<6144, 256, 0, stream>>>(x, h, Wx, Wh, Ap, Wt2);
  lstm_gemm_kernel<<<dim3(512), dim3(512), LDS_TOTAL, stream>>>(Ap, Wt2, c, out);
}